// Round 8
// baseline (752.150 us; speedup 1.0000x reference)
//
#include <hip/hip_runtime.h>

#define LK   50      // look_back
#define NOUT 3
#define FF   64      // feature_num
#define BB   2048    // batch
#define HH   128     // units
#define BT   8       // batch rows per workgroup
#define NWG  (BB/BT) // 256 workgroups
#define NTHR 1024    // 16 waves

typedef unsigned short u16;
typedef unsigned int   u32;
typedef __attribute__((ext_vector_type(8))) short short8;
typedef __attribute__((ext_vector_type(4))) float f32x4;

#define MFMA16(a,b,c) __builtin_amdgcn_mfma_f32_16x16x32_bf16(a,b,c,0,0,0)

// pre-converted bf16 buffers (device globals; rewritten every launch)
__device__ u16 g_xbf [(size_t)BB*LK*FF];   // x,        [b][t][f]
__device__ u16 g_awT [(size_t)LK*64*192];  // attn_w^T, [t][c][k]  k:[xt(64)|h(128)]
__device__ u16 g_eW  [512*192];            // enc LSTM, [gate][k]  k:[xin(64)|h(128)]
__device__ u16 g_dW  [512*384];            // dec LSTM, [gate][k]  k:[ctx(128)|h(128)|h(128)]
__device__ u16 g_ddwT[NOUT*128*256];       // dd_w^T,   [s][n][k]  k:[enc(128)|h(128)]
__device__ u16 g_fcwT[NOUT*64*128];        // fc_w^T,   [s][n][k]
__device__ u16 g_encbf[(size_t)BB*LK*256]; // encoder outputs hi/lo: [b][t][hi(128)|lo(128)]

__device__ __forceinline__ float sigf(float x) { return 1.0f / (1.0f + __expf(-x)); }
__device__ __forceinline__ float tanhff(float x) { return 1.0f - 2.0f / (__expf(2.0f * x) + 1.0f); }
__device__ __forceinline__ u16 f2b(float f) {
    union { float f; u32 u; } v; v.f = f;
    u32 r = v.u + 0x7fffu + ((v.u >> 16) & 1u);
    return (u16)(r >> 16);
}
__device__ __forceinline__ float b2f(u16 h) {
    union { u32 u; float f; } v; v.u = ((u32)h) << 16; return v.f;
}

// coalesced-read convert (verified layouts, R7)
__global__ __launch_bounds__(256)
void convert_kernel(const float* __restrict__ x,
                    const float* __restrict__ eWih, const float* __restrict__ eWhh,
                    const float* __restrict__ aw,
                    const float* __restrict__ dWih, const float* __restrict__ dWhh,
                    const float* __restrict__ ddw,  const float* __restrict__ fcw)
{
    const int gid = blockIdx.x * blockDim.x + threadIdx.x;
    const int stride = gridDim.x * blockDim.x;
    {
        const float2* xs = (const float2*)x;
        u32* xd = (u32*)g_xbf;
        for (int i = gid; i < BB*LK*FF/2; i += stride) {
            float2 v = xs[i];
            xd[i] = (u32)f2b(v.x) | ((u32)f2b(v.y) << 16);
        }
    }
    for (int i = gid; i < LK*192*64; i += stride) {
        int t = i / 12288, rm = i % 12288, k = rm / 64, c = rm % 64;
        g_awT[(size_t)t*12288 + c*192 + k] = f2b(aw[i]);
    }
    for (int i = gid; i < 512*192; i += stride) {
        int j = i / 192, k = i % 192;
        g_eW[i] = f2b(k < 64 ? eWih[j*64 + k] : eWhh[j*128 + (k-64)]);
    }
    for (int i = gid; i < 512*384; i += stride) {
        int j = i / 384, k = i % 384;
        g_dW[i] = f2b(k < 256 ? dWih[j*256 + k] : dWhh[j*128 + (k-256)]);
    }
    for (int i = gid; i < NOUT*256*128; i += stride) {
        int s = i / 32768, rm = i % 32768, k = rm / 128, n = rm % 128;
        g_ddwT[(size_t)s*32768 + n*256 + k] = f2b(ddw[i]);
    }
    for (int i = gid; i < NOUT*128*64; i += stride) {
        int s = i / 8192, rm = i % 8192, k = rm / 64, n = rm % 64;
        g_fcwT[(size_t)s*8192 + n*128 + k] = f2b(fcw[i]);
    }
}

// chunk(32-wide) -> B k-offset for A=[x(64)|h_hi(128)|h_lo(128)] vs B=[x(64)|h(128)]
__device__ __forceinline__ int bk_enc(int c) { return c < 2 ? c*32 : 64 + ((c-2)&3)*32; }

__global__ __launch_bounds__(NTHR, 4)
void darnn_kernel(const float* __restrict__ ab,
                  const float* __restrict__ ebih, const float* __restrict__ ebhh,
                  const float* __restrict__ dbih, const float* __restrict__ dbhh,
                  const float* __restrict__ ddb,
                  const float* __restrict__ dlw,  const float* __restrict__ dlb,
                  const float* __restrict__ fcb,
                  const float* __restrict__ ow,   const float* __restrict__ ob,
                  float* __restrict__ out)
{
    // pitches chosen ≡8 mod 32 dwords (4-way max bank aliasing); rows 8..15 stay zero
    __shared__ u16  s_x[2][16][80];     // x(t) ping-pong
    __shared__ u16  s_xin[16][80];      // xin after input-attention softmax
    __shared__ u16  s_h[16][272];       // encoder h: [hi(0:128)|lo(128:256)]
    __shared__ u16  s_Adec[16][528];    // decoder A [ctx_hi|ctx_lo|h_hi(256:384)|h_lo(384:512)]
    __shared__ float s_e[8][64];        // attn pre-tanh scores
    __shared__ float s_c[8][128];       // cell state fp32 (enc, then dec)
    __shared__ float s_g[512][9];       // gate partials (decoder only)
    __shared__ float s_hp[8][128];      // decoder hpart
    __shared__ float s_spart[4][400];   // score partials
    __shared__ float s_alpha[8][64];    // temporal attn weights
    __shared__ float s_y1[8][64];       // head intermediate
    __shared__ float s_ebias[512];
    __shared__ float s_dbias[512];

    const int tid  = threadIdx.x;
    const int b0   = blockIdx.x * BT;
    const int wv   = tid >> 6;
    const int lane = tid & 63;
    const int quad = lane >> 4;
    const int l16  = lane & 15;
    const int gw   = wv - 4;            // gate-wave unit-group, valid for wv in [4,12)

    // ---- preamble ----
    for (int i = tid; i < 2*16*80; i += NTHR) (&s_x[0][0][0])[i] = 0;
    for (int i = tid; i < 16*80;   i += NTHR) (&s_xin[0][0])[i] = 0;
    for (int i = tid; i < 16*272;  i += NTHR) (&s_h[0][0])[i] = 0;
    for (int i = tid; i < 16*528;  i += NTHR) (&s_Adec[0][0])[i] = 0;
    (&s_c[0][0])[tid] = 0.0f;
    if (tid < 512) { s_ebias[tid] = ebih[tid] + ebhh[tid]; s_dbias[tid] = dbih[tid] + dbhh[tid]; }
    if (tid < 512) {
        int r = tid >> 6, f = tid & 63;
        s_x[0][r][f] = g_xbf[((size_t)(b0 + r) * LK + 0) * FF + f];
    }
    __syncthreads();

    // ================= ENCODER: 50 steps, 3 barriers each =================
#pragma unroll 1
    for (int t = 0; t < LK; ++t) {
        const int pb = t & 1;
        f32x4 ai = {0.f,0.f,0.f,0.f}, af = ai, ag = ai, ao = ai;  // persist P1->P3

        // --- P1: attn-e (wv 0-3) || gates h-part (wv 4-11) || x prefetch (wv 12-15) ---
        if (wv < 4) {
            const int f0 = wv * 16 + l16;
            const u16* bp = g_awT + (size_t)t * 12288 + f0 * 192 + quad * 8;
            f32x4 acc = {0.f,0.f,0.f,0.f};
#pragma unroll
            for (int c = 0; c < 10; ++c) {
                const u16* ap = (c < 2) ? &s_x[pb][l16][c*32 + quad*8]
                                        : &s_h[l16][(c-2)*32 + quad*8];
                acc = MFMA16(*(const short8*)ap, *(const short8*)(bp + bk_enc(c)), acc);
            }
            const float abv = ab[t * FF + f0];
            if (quad < 2) {
#pragma unroll
                for (int rg = 0; rg < 4; ++rg) s_e[quad*4 + rg][f0] = acc[rg] + abv;
            }
        } else if (wv < 12) {
            // full coverage: wave gw owns i,f,g,o tiles for units [16gw,16gw+16)
            const u16* b_i = g_eW + (size_t)(gw*16 + l16) * 192 + quad * 8;
#pragma unroll
            for (int c = 2; c < 10; ++c) {
                short8 av = *(const short8*)&s_h[l16][(c-2)*32 + quad*8];
                const int bo = bk_enc(c);
                ai = MFMA16(av, *(const short8*)(b_i + bo),           ai);
                af = MFMA16(av, *(const short8*)(b_i + 128*192 + bo), af);
                ag = MFMA16(av, *(const short8*)(b_i + 256*192 + bo), ag);
                ao = MFMA16(av, *(const short8*)(b_i + 384*192 + bo), ao);
            }
        } else {
            if (t + 1 < LK) {
                const int ii = tid - 768;            // 0..255
                const int r = ii >> 5, p = ii & 31;  // 32 u32 per row
                const u32* src = (const u32*)g_xbf + ((size_t)(b0 + r) * LK + (t + 1)) * 32 + p;
                *((u32*)&s_x[pb^1][r][0] + p) = *src;
            }
        }
        __syncthreads();

        // --- P2: softmax over 64 features (wave per row); xin = smax(tanh(e)) * x ---
        if (tid < 512) {
            const int r = tid >> 6;
            float e = tanhff(s_e[r][lane]);
            float mx = e;
#pragma unroll
            for (int m = 1; m < 64; m <<= 1) mx = fmaxf(mx, __shfl_xor(mx, m, 64));
            float ex = __expf(e - mx);
            float sm = ex;
#pragma unroll
            for (int m = 1; m < 64; m <<= 1) sm += __shfl_xor(sm, m, 64);
            s_xin[r][lane] = f2b(ex / sm * b2f(s_x[pb][r][lane]));
        }
        __syncthreads();

        // --- P3: gates xin-part + in-lane combine + state update + stores ---
        if (wv >= 4 && wv < 12) {
            const u16* b_i = g_eW + (size_t)(gw*16 + l16) * 192 + quad * 8;
#pragma unroll
            for (int c = 0; c < 2; ++c) {
                short8 av = *(const short8*)&s_xin[l16][c*32 + quad*8];
                const int bo = c * 32;
                ai = MFMA16(av, *(const short8*)(b_i + bo),           ai);
                af = MFMA16(av, *(const short8*)(b_i + 128*192 + bo), af);
                ag = MFMA16(av, *(const short8*)(b_i + 256*192 + bo), ag);
                ao = MFMA16(av, *(const short8*)(b_i + 384*192 + bo), ao);
            }
            if (quad < 2) {
                const int u = gw*16 + l16;
                const float bi_ = s_ebias[u],       bf_ = s_ebias[128 + u];
                const float bg_ = s_ebias[256 + u], bo_ = s_ebias[384 + u];
#pragma unroll
                for (int rg = 0; rg < 4; ++rg) {
                    const int r = quad*4 + rg;
                    float cc = sigf(af[rg] + bf_) * s_c[r][u] + sigf(ai[rg] + bi_) * tanhff(ag[rg] + bg_);
                    float hh = sigf(ao[rg] + bo_) * tanhff(cc);
                    s_c[r][u] = cc;
                    u16 hi = f2b(hh), lo = f2b(hh - b2f(hi));
                    s_h[r][u]       = hi;
                    s_h[r][128 + u] = lo;
                    size_t eb = ((size_t)(b0 + r) * LK + t) * 256;
                    g_encbf[eb + u]       = hi;
                    g_encbf[eb + 128 + u] = lo;
                }
            }
        }
        __syncthreads();
    }

    // ================= DECODER: 3 steps (R6-verified dataflow) =================
    (&s_c[0][0])[tid] = 0.0f;   // s_Adec still zero from init
    __syncthreads();

#pragma unroll 1
    for (int s = 0; s < NOUT; ++s) {
        // D1: hpart = h_de(hi/lo) @ ddw[128:,:] + ddb  (8 waves)
        if (wv < 8) {
            const int n = wv * 16 + l16;
            f32x4 acc = {0.f,0.f,0.f,0.f};
            const u16* bp = g_ddwT + s * 32768 + n * 256 + 128 + quad * 8;
#pragma unroll
            for (int c = 0; c < 8; ++c) {
                short8 av = *(const short8*)&s_Adec[l16][256 + c*32 + quad*8];
                acc = MFMA16(av, *(const short8*)(bp + (c&3)*32), acc);
            }
            float db = ddb[s * 128 + n];
            if (quad < 2) {
#pragma unroll
                for (int rg = 0; rg < 4; ++rg) s_hp[quad*4 + rg][n] = acc[rg] + db;
            }
        }
        __syncthreads();

        // D2: score GEMM [400, 256-A(hi/lo)] x [128-B, 128]
        {
            const int np = wv & 3, mq = wv >> 2, nb0 = np * 32;
            short8 bfr[8];
            const u16* bp = g_ddwT + s * 32768 + (nb0 + l16) * 256 + quad * 8;
#pragma unroll
            for (int nn = 0; nn < 2; ++nn)
#pragma unroll
                for (int ks = 0; ks < 4; ++ks)
                    bfr[nn*4+ks] = *(const short8*)(bp + nn*4096 + ks*32);
            const float dl0 = dlw[s*128 + nb0 + l16];
            const float dl1 = dlw[s*128 + nb0 + 16 + l16];
#pragma unroll 1
            for (int mt = mq; mt < 25; mt += 4) {
                const u16* ap = g_encbf + ((size_t)b0 * LK + mt*16 + l16) * 256 + quad * 8;
                f32x4 a0 = {0.f,0.f,0.f,0.f}, a1 = {0.f,0.f,0.f,0.f};
#pragma unroll
                for (int c = 0; c < 8; ++c) {
                    short8 av = *(const short8*)(ap + c*32);
                    a0 = MFMA16(av, bfr[c&3],     a0);
                    a1 = MFMA16(av, bfr[4+(c&3)], a1);
                }
#pragma unroll
                for (int rg = 0; rg < 4; ++rg) {
                    int rt = mt*16 + quad*4 + rg;
                    int r  = rt / LK;
                    float v = tanhff(a0[rg] + s_hp[r][nb0 + l16]) * dl0
                            + tanhff(a1[rg] + s_hp[r][nb0 + 16 + l16]) * dl1;
                    v += __shfl_xor(v, 1, 64); v += __shfl_xor(v, 2, 64);
                    v += __shfl_xor(v, 4, 64); v += __shfl_xor(v, 8, 64);
                    if (l16 == 0) s_spart[np][rt] = v;
                }
            }
        }
        __syncthreads();

        // D3: softmax over t (wave per row)
        if (tid < 512) {
            const int r = tid >> 6;
            float sv = (lane < LK)
                ? (s_spart[0][r*LK + lane] + s_spart[1][r*LK + lane] +
                   s_spart[2][r*LK + lane] + s_spart[3][r*LK + lane] + dlb[s])
                : -1e30f;
            float mx = sv;
#pragma unroll
            for (int m = 1; m < 64; m <<= 1) mx = fmaxf(mx, __shfl_xor(mx, m, 64));
            float ex = (lane < LK) ? __expf(sv - mx) : 0.0f;
            float sm = ex;
#pragma unroll
            for (int m = 1; m < 64; m <<= 1) sm += __shfl_xor(sm, m, 64);
            if (lane < LK) s_alpha[r][lane] = ex / sm;
        }
        __syncthreads();

        // D4: ctx = sum_t alpha * (enc_hi + enc_lo) in fp32; store ctx hi/lo
        {
            const int jd = tid & 127, r = tid >> 7;
            const u16* ep = g_encbf + (size_t)(b0 + r) * LK * 256 + jd;
            float a = 0.0f;
#pragma unroll 10
            for (int tt = 0; tt < LK; ++tt)
                a += s_alpha[r][tt] * (b2f(ep[tt*256]) + b2f(ep[tt*256 + 128]));
            u16 hi = f2b(a);
            s_Adec[r][jd]       = hi;
            s_Adec[r][128 + jd] = f2b(a - b2f(hi));
        }
        __syncthreads();

        // D5: decoder LSTM gates [16, 768-A(hi/lo)] x [384-B, 512] — full K per wave
        {
            const int n0 = wv * 32;
            f32x4 a0 = {0.f,0.f,0.f,0.f}, a1 = {0.f,0.f,0.f,0.f};
            const u16* bp0 = g_dW + (n0 + l16) * 384 + quad * 8;
            const u16* bp1 = bp0 + 16 * 384;
#pragma unroll
            for (int c = 0; c < 24; ++c) {
                const int g = c >> 2, o = (c & 3) * 32;
                const int aoff = (g < 2 ? g*128 : 256 + (g & 1)*128) + o;  // A col
                const int boff = ((g >> 1) << 7) + o;                       // B k-offset
                short8 av = *(const short8*)&s_Adec[l16][aoff + quad*8];
                a0 = MFMA16(av, *(const short8*)(bp0 + boff), a0);
                a1 = MFMA16(av, *(const short8*)(bp1 + boff), a1);
            }
            if (quad < 2) {
#pragma unroll
                for (int rg = 0; rg < 4; ++rg) {
                    int r = quad*4 + rg;
                    s_g[n0 + l16][r]      = a0[rg];
                    s_g[n0 + 16 + l16][r] = a1[rg];
                }
            }
        }
        __syncthreads();

        // D6: gate combine + state update (hi/lo)
        {
            const int u = tid & 127, r = tid >> 7;
            float gi = s_g[u][r]       + s_dbias[u];
            float gf = s_g[128 + u][r] + s_dbias[128 + u];
            float gg = s_g[256 + u][r] + s_dbias[256 + u];
            float go = s_g[384 + u][r] + s_dbias[384 + u];
            float c = sigf(gf) * s_c[r][u] + sigf(gi) * tanhff(gg);
            float h = sigf(go) * tanhff(c);
            s_c[r][u] = c;
            u16 hi = f2b(h);
            s_Adec[r][256 + u] = hi;
            s_Adec[r][384 + u] = f2b(h - b2f(hi));
        }
        __syncthreads();

        // D7: head y1 = tanh(h(hi/lo) @ fc_w + fc_b) (4 waves)
        if (wv < 4) {
            const int n = wv * 16 + l16;
            f32x4 acc = {0.f,0.f,0.f,0.f};
            const u16* bp = g_fcwT + s * 8192 + n * 128 + quad * 8;
#pragma unroll
            for (int c = 0; c < 8; ++c) {
                short8 av = *(const short8*)&s_Adec[l16][256 + c*32 + quad*8];
                acc = MFMA16(av, *(const short8*)(bp + (c&3)*32), acc);
            }
            float fb = fcb[s * 64 + n];
            if (quad < 2) {
#pragma unroll
                for (int rg = 0; rg < 4; ++rg) s_y1[quad*4 + rg][n] = tanhff(acc[rg] + fb);
            }
        }
        __syncthreads();

        // D8: out = sigmoid(y1 @ out_w + out_b)
        if (tid < 512) {
            const int r = tid >> 6;
            float v = s_y1[r][lane] * ow[s * 64 + lane];
#pragma unroll
            for (int m = 1; m < 64; m <<= 1) v += __shfl_xor(v, m, 64);
            if (lane == 0) out[(b0 + r) * NOUT + s] = sigf(v + ob[s]);
        }
        __syncthreads();
    }
}

extern "C" void kernel_launch(void* const* d_in, const int* in_sizes, int n_in,
                              void* d_out, int out_size, void* d_ws, size_t ws_size,
                              hipStream_t stream) {
    const float* x    = (const float*)d_in[0];
    const float* eWih = (const float*)d_in[1];
    const float* eWhh = (const float*)d_in[2];
    const float* ebih = (const float*)d_in[3];
    const float* ebhh = (const float*)d_in[4];
    const float* aw   = (const float*)d_in[5];
    const float* ab   = (const float*)d_in[6];
    const float* dWih = (const float*)d_in[7];
    const float* dWhh = (const float*)d_in[8];
    const float* dbih = (const float*)d_in[9];
    const float* dbhh = (const float*)d_in[10];
    const float* ddw  = (const float*)d_in[11];
    const float* ddb  = (const float*)d_in[12];
    const float* dlw  = (const float*)d_in[13];
    const float* dlb  = (const float*)d_in[14];
    const float* fcw  = (const float*)d_in[15];
    const float* fcb  = (const float*)d_in[16];
    const float* ow   = (const float*)d_in[17];
    const float* ob   = (const float*)d_in[18];
    float* out = (float*)d_out;

    convert_kernel<<<1280, 256, 0, stream>>>(x, eWih, eWhh, aw, dWih, dWhh, ddw, fcw);
    darnn_kernel<<<NWG, NTHR, 0, stream>>>(ab, ebih, ebhh, dbih, dbhh, ddb,
                                           dlw, dlb, fcb, ow, ob, out);
}

// Round 9
// 431.492 us; speedup vs baseline: 1.7431x; 1.7431x over previous
//
#include <hip/hip_runtime.h>

#define LK   50      // look_back
#define NOUT 3
#define FF   64      // feature_num
#define BB   2048    // batch
#define HH   128     // units
#define BT   8       // batch rows per workgroup
#define NWG  (BB/BT) // 256 workgroups
#define NTHR 1024    // 16 waves

typedef unsigned short u16;
typedef unsigned int   u32;
typedef __attribute__((ext_vector_type(8))) short short8;
typedef __attribute__((ext_vector_type(4))) float f32x4;

#define MFMA16(a,b,c) __builtin_amdgcn_mfma_f32_16x16x32_bf16(a,b,c,0,0,0)

// pre-converted bf16 buffers (device globals; rewritten every launch)
__device__ u16 g_xbf [(size_t)BB*LK*FF];   // x,        [b][t][f]
__device__ u16 g_awT [(size_t)LK*64*192];  // attn_w^T, [t][c][k]  k:[xt(64)|h(128)]
__device__ u16 g_eW  [512*192];            // enc LSTM, [gate][k]  k:[xin(64)|h(128)]
__device__ u16 g_dW  [512*384];            // dec LSTM, [gate][k]  k:[ctx(128)|h(128)|h(128)]
__device__ u16 g_ddwT[NOUT*128*256];       // dd_w^T,   [s][n][k]  k:[enc(128)|h(128)]
__device__ u16 g_fcwT[NOUT*64*128];        // fc_w^T,   [s][n][k]
__device__ u16 g_encbf[(size_t)BB*LK*256]; // encoder outputs hi/lo: [b][t][hi(128)|lo(128)]

__device__ __forceinline__ float sigf(float x) { return 1.0f / (1.0f + __expf(-x)); }
__device__ __forceinline__ float tanhff(float x) { return 1.0f - 2.0f / (__expf(2.0f * x) + 1.0f); }
__device__ __forceinline__ u16 f2b(float f) {
    union { float f; u32 u; } v; v.f = f;
    u32 r = v.u + 0x7fffu + ((v.u >> 16) & 1u);
    return (u16)(r >> 16);
}
__device__ __forceinline__ float b2f(u16 h) {
    union { u32 u; float f; } v; v.u = ((u32)h) << 16; return v.f;
}

// main convert (awT handled by conv_awT below)
__global__ __launch_bounds__(256)
void convert_kernel(const float* __restrict__ x,
                    const float* __restrict__ eWih, const float* __restrict__ eWhh,
                    const float* __restrict__ dWih, const float* __restrict__ dWhh,
                    const float* __restrict__ ddw,  const float* __restrict__ fcw)
{
    const int gid = blockIdx.x * blockDim.x + threadIdx.x;
    const int stride = gridDim.x * blockDim.x;
    {
        const float2* xs = (const float2*)x;
        u32* xd = (u32*)g_xbf;
        for (int i = gid; i < BB*LK*FF/2; i += stride) {
            float2 v = xs[i];
            xd[i] = (u32)f2b(v.x) | ((u32)f2b(v.y) << 16);
        }
    }
    for (int i = gid; i < 512*192; i += stride) {
        int j = i / 192, k = i % 192;
        g_eW[i] = f2b(k < 64 ? eWih[j*64 + k] : eWhh[j*128 + (k-64)]);
    }
    for (int i = gid; i < 512*384; i += stride) {
        int j = i / 384, k = i % 384;
        g_dW[i] = f2b(k < 256 ? dWih[j*256 + k] : dWhh[j*128 + (k-256)]);
    }
    for (int i = gid; i < NOUT*256*128; i += stride) {
        int s = i / 32768, rm = i % 32768, k = rm / 128, n = rm % 128;
        g_ddwT[(size_t)s*32768 + n*256 + k] = f2b(ddw[i]);
    }
    for (int i = gid; i < NOUT*128*64; i += stride) {
        int s = i / 8192, rm = i % 8192, k = rm / 64, n = rm % 64;
        g_fcwT[(size_t)s*8192 + n*128 + k] = f2b(fcw[i]);
    }
}

// LDS-tiled awT transpose: one block per t; coalesced read AND write
__global__ __launch_bounds__(256)
void conv_awT(const float* __restrict__ aw)
{
    __shared__ u16 tile[192*66];   // [k][c], pitch 66 (bank-spread)
    const int t = blockIdx.x, tid = threadIdx.x;
    for (int i = tid; i < 192*64; i += 256) {
        int k = i >> 6, c = i & 63;
        tile[k*66 + c] = f2b(aw[(size_t)t*12288 + i]);   // aw[t][k][c], coalesced
    }
    __syncthreads();
    u32* dst = (u32*)g_awT + (size_t)t * 6144;
    for (int j = tid; j < 6144; j += 256) {              // [c][k] row-major, coalesced
        int c = j / 96, w = j % 96;
        u32 v = (u32)tile[(2*w)*66 + c] | ((u32)tile[(2*w+1)*66 + c] << 16);
        dst[j] = v;
    }
}

// A-chunk c (of 10: x 0-1, h_hi 2-5, h_lo 6-9) -> unique B chunk index (of 6)
__device__ __forceinline__ int uc_of(int c) { return c < 2 ? c : 2 + ((c-2)&3); }

__global__ __launch_bounds__(NTHR, 4)
void darnn_kernel(const float* __restrict__ ab,
                  const float* __restrict__ ebih, const float* __restrict__ ebhh,
                  const float* __restrict__ dbih, const float* __restrict__ dbhh,
                  const float* __restrict__ ddb,
                  const float* __restrict__ dlw,  const float* __restrict__ dlb,
                  const float* __restrict__ fcb,
                  const float* __restrict__ ow,   const float* __restrict__ ob,
                  float* __restrict__ out)
{
    __shared__ u16  s_x[2][16][80];     // x(t) ping-pong; rows 8..15 zero
    __shared__ u16  s_xin[16][80];      // xin after input-attention softmax
    __shared__ u16  s_h[16][272];       // encoder h: [hi(0:128)|lo(128:256)]
    __shared__ u16  s_Adec[16][528];    // decoder A [ctx_hi|ctx_lo|h_hi(256:384)|h_lo(384:512)]
    __shared__ float s_e[8][64];        // attn pre-tanh scores
    __shared__ float s_c[8][128];       // cell state fp32
    __shared__ float s_g[512][9];       // gate partials
    __shared__ float s_hp[8][128];      // decoder hpart
    __shared__ float s_spart[4][400];   // score partials
    __shared__ float s_alpha[8][64];    // temporal attn weights
    __shared__ float s_y1[8][64];       // head intermediate
    __shared__ float s_ebias[512];
    __shared__ float s_dbias[512];

    const int tid  = threadIdx.x;
    const int b0   = blockIdx.x * BT;
    const int wv   = tid >> 6;
    const int lane = tid & 63;
    const int quad = lane >> 4;
    const int l16  = lane & 15;
    const int n0   = wv * 32;           // this wave's 2 gate n-tiles: n0, n0+16

    // ---- preamble ----
    for (int i = tid; i < 2*16*80; i += NTHR) (&s_x[0][0][0])[i] = 0;
    for (int i = tid; i < 16*80;   i += NTHR) (&s_xin[0][0])[i] = 0;
    for (int i = tid; i < 16*272;  i += NTHR) (&s_h[0][0])[i] = 0;
    for (int i = tid; i < 16*528;  i += NTHR) (&s_Adec[0][0])[i] = 0;
    (&s_c[0][0])[tid & 1023] = 0.0f;
    if (tid < 512) { s_ebias[tid] = ebih[tid] + ebhh[tid]; s_dbias[tid] = dbih[tid] + dbhh[tid]; }
    if (tid < 512) {
        int r = tid >> 6, f = tid & 63;
        s_x[0][r][f] = g_xbf[((size_t)(b0 + r) * LK + 0) * FF + f];
    }
    // pin full eW B-set: 2 tiles x 6 unique chunks = 12 short8 = 48 VGPRs, whole t-loop
    short8 wf[12];
#pragma unroll
    for (int nn = 0; nn < 2; ++nn)
#pragma unroll
        for (int uc = 0; uc < 6; ++uc)
            wf[nn*6+uc] = *(const short8*)(g_eW + (size_t)(n0 + nn*16 + l16) * 192 + uc*32 + quad*8);
    __syncthreads();

    // ================= ENCODER: 50 steps, 4 barriers each =================
#pragma unroll 1
    for (int t = 0; t < LK; ++t) {
        const int pb = t & 1;

        // --- P1: attention e (waves 0-3; B-frags batch-loaded) ---
        if (wv < 4) {
            const int f0 = wv * 16 + l16;
            const u16* bp = g_awT + (size_t)t * 12288 + f0 * 192 + quad * 8;
            short8 bfr[6];
#pragma unroll
            for (int uc = 0; uc < 6; ++uc) bfr[uc] = *(const short8*)(bp + uc*32);
            f32x4 acc = {0.f,0.f,0.f,0.f};
#pragma unroll
            for (int c = 0; c < 10; ++c) {
                const u16* ap = (c < 2) ? &s_x[pb][l16][c*32 + quad*8]
                                        : &s_h[l16][(c-2)*32 + quad*8];
                acc = MFMA16(*(const short8*)ap, bfr[uc_of(c)], acc);
            }
            const float abv = ab[t * FF + f0];
            if (quad < 2) {
#pragma unroll
                for (int rg = 0; rg < 4; ++rg) s_e[quad*4 + rg][f0] = acc[rg] + abv;
            }
        }
        __syncthreads();

        // --- P2: softmax (waves 0-7) || x(t+1) prefetch (waves 8-11) ---
        if (tid < 512) {
            const int r = tid >> 6;
            float e = tanhff(s_e[r][lane]);
            float mx = e;
#pragma unroll
            for (int m = 1; m < 64; m <<= 1) mx = fmaxf(mx, __shfl_xor(mx, m, 64));
            float ex = __expf(e - mx);
            float sm = ex;
#pragma unroll
            for (int m = 1; m < 64; m <<= 1) sm += __shfl_xor(sm, m, 64);
            s_xin[r][lane] = f2b(ex / sm * b2f(s_x[pb][r][lane]));
        } else if (tid < 768) {
            if (t + 1 < LK) {
                const int ii = tid - 512;            // 0..255
                const int r = ii >> 5, p = ii & 31;  // 32 u32 per row
                *((u32*)&s_x[pb^1][r][0] + p) =
                    *((const u32*)g_xbf + ((size_t)(b0 + r) * LK + (t + 1)) * 32 + p);
            }
        }
        __syncthreads();

        // --- P3: gate GEMM, all 16 waves, ZERO loads (B pinned) ---
        {
            f32x4 a0 = {0.f,0.f,0.f,0.f}, a1 = {0.f,0.f,0.f,0.f};
#pragma unroll
            for (int c = 0; c < 10; ++c) {
                const u16* ap = (c < 2) ? &s_xin[l16][c*32 + quad*8]
                                        : &s_h[l16][(c-2)*32 + quad*8];
                short8 av = *(const short8*)ap;
                const int uc = uc_of(c);
                a0 = MFMA16(av, wf[uc],   a0);
                a1 = MFMA16(av, wf[6+uc], a1);
            }
            if (quad < 2) {
#pragma unroll
                for (int rg = 0; rg < 4; ++rg) {
                    int r = quad*4 + rg;
                    s_g[n0 + l16][r]      = a0[rg];
                    s_g[n0 + 16 + l16][r] = a1[rg];
                }
            }
        }
        __syncthreads();

        // --- P4: gate combine + state update (hi/lo) + enc store ---
        {
            const int u = tid & 127, r = tid >> 7;
            float gi = s_g[u][r]       + s_ebias[u];
            float gf = s_g[128 + u][r] + s_ebias[128 + u];
            float gg = s_g[256 + u][r] + s_ebias[256 + u];
            float go = s_g[384 + u][r] + s_ebias[384 + u];
            float c = sigf(gf) * s_c[r][u] + sigf(gi) * tanhff(gg);
            float h = sigf(go) * tanhff(c);
            s_c[r][u] = c;
            u16 hi = f2b(h);
            u16 lo = f2b(h - b2f(hi));
            s_h[r][u]       = hi;
            s_h[r][128 + u] = lo;
            size_t eb = ((size_t)(b0 + r) * LK + t) * 256;
            g_encbf[eb + u]       = hi;
            g_encbf[eb + 128 + u] = lo;
        }
        __syncthreads();
    }

    // ================= DECODER: 3 steps (R8-verified dataflow) =================
    (&s_c[0][0])[tid & 1023] = 0.0f;   // s_Adec still zero from init
    __syncthreads();

#pragma unroll 1
    for (int s = 0; s < NOUT; ++s) {
        // D1: hpart = h_de(hi/lo) @ ddw[128:,:] + ddb  (8 waves)
        if (wv < 8) {
            const int n = wv * 16 + l16;
            f32x4 acc = {0.f,0.f,0.f,0.f};
            const u16* bp = g_ddwT + s * 32768 + n * 256 + 128 + quad * 8;
#pragma unroll
            for (int c = 0; c < 8; ++c) {
                short8 av = *(const short8*)&s_Adec[l16][256 + c*32 + quad*8];
                acc = MFMA16(av, *(const short8*)(bp + (c&3)*32), acc);
            }
            float db = ddb[s * 128 + n];
            if (quad < 2) {
#pragma unroll
                for (int rg = 0; rg < 4; ++rg) s_hp[quad*4 + rg][n] = acc[rg] + db;
            }
        }
        __syncthreads();

        // D2: score GEMM [400, 256-A(hi/lo)] x [128-B, 128]
        {
            const int np = wv & 3, mq = wv >> 2, nb0 = np * 32;
            short8 bfr[8];
            const u16* bp = g_ddwT + s * 32768 + (nb0 + l16) * 256 + quad * 8;
#pragma unroll
            for (int nn = 0; nn < 2; ++nn)
#pragma unroll
                for (int ks = 0; ks < 4; ++ks)
                    bfr[nn*4+ks] = *(const short8*)(bp + nn*4096 + ks*32);
            const float dl0 = dlw[s*128 + nb0 + l16];
            const float dl1 = dlw[s*128 + nb0 + 16 + l16];
#pragma unroll 1
            for (int mt = mq; mt < 25; mt += 4) {
                const u16* ap = g_encbf + ((size_t)b0 * LK + mt*16 + l16) * 256 + quad * 8;
                f32x4 a0 = {0.f,0.f,0.f,0.f}, a1 = {0.f,0.f,0.f,0.f};
#pragma unroll
                for (int c = 0; c < 8; ++c) {
                    short8 av = *(const short8*)(ap + c*32);
                    a0 = MFMA16(av, bfr[c&3],     a0);
                    a1 = MFMA16(av, bfr[4+(c&3)], a1);
                }
#pragma unroll
                for (int rg = 0; rg < 4; ++rg) {
                    int rt = mt*16 + quad*4 + rg;
                    int r  = rt / LK;
                    float v = tanhff(a0[rg] + s_hp[r][nb0 + l16]) * dl0
                            + tanhff(a1[rg] + s_hp[r][nb0 + 16 + l16]) * dl1;
                    v += __shfl_xor(v, 1, 64); v += __shfl_xor(v, 2, 64);
                    v += __shfl_xor(v, 4, 64); v += __shfl_xor(v, 8, 64);
                    if (l16 == 0) s_spart[np][rt] = v;
                }
            }
        }
        __syncthreads();

        // D3: softmax over t (wave per row)
        if (tid < 512) {
            const int r = tid >> 6;
            float sv = (lane < LK)
                ? (s_spart[0][r*LK + lane] + s_spart[1][r*LK + lane] +
                   s_spart[2][r*LK + lane] + s_spart[3][r*LK + lane] + dlb[s])
                : -1e30f;
            float mx = sv;
#pragma unroll
            for (int m = 1; m < 64; m <<= 1) mx = fmaxf(mx, __shfl_xor(mx, m, 64));
            float ex = (lane < LK) ? __expf(sv - mx) : 0.0f;
            float sm = ex;
#pragma unroll
            for (int m = 1; m < 64; m <<= 1) sm += __shfl_xor(sm, m, 64);
            if (lane < LK) s_alpha[r][lane] = ex / sm;
        }
        __syncthreads();

        // D4: ctx = sum_t alpha * (enc_hi + enc_lo) in fp32; store ctx hi/lo
        {
            const int jd = tid & 127, r = tid >> 7;
            const u16* ep = g_encbf + (size_t)(b0 + r) * LK * 256 + jd;
            float a = 0.0f;
#pragma unroll 10
            for (int tt = 0; tt < LK; ++tt)
                a += s_alpha[r][tt] * (b2f(ep[tt*256]) + b2f(ep[tt*256 + 128]));
            u16 hi = f2b(a);
            s_Adec[r][jd]       = hi;
            s_Adec[r][128 + jd] = f2b(a - b2f(hi));
        }
        __syncthreads();

        // D5: decoder LSTM gates [16, 768-A(hi/lo)] x [384-B, 512] — full K per wave
        {
            const int nd0 = wv * 32;
            f32x4 a0 = {0.f,0.f,0.f,0.f}, a1 = {0.f,0.f,0.f,0.f};
            const u16* bp0 = g_dW + (nd0 + l16) * 384 + quad * 8;
            const u16* bp1 = bp0 + 16 * 384;
#pragma unroll
            for (int c = 0; c < 24; ++c) {
                const int g = c >> 2, o = (c & 3) * 32;
                const int aoff = (g < 2 ? g*128 : 256 + (g & 1)*128) + o;  // A col
                const int boff = ((g >> 1) << 7) + o;                       // B k-offset
                short8 av = *(const short8*)&s_Adec[l16][aoff + quad*8];
                a0 = MFMA16(av, *(const short8*)(bp0 + boff), a0);
                a1 = MFMA16(av, *(const short8*)(bp1 + boff), a1);
            }
            if (quad < 2) {
#pragma unroll
                for (int rg = 0; rg < 4; ++rg) {
                    int r = quad*4 + rg;
                    s_g[nd0 + l16][r]      = a0[rg];
                    s_g[nd0 + 16 + l16][r] = a1[rg];
                }
            }
        }
        __syncthreads();

        // D6: gate combine + state update (hi/lo)
        {
            const int u = tid & 127, r = tid >> 7;
            float gi = s_g[u][r]       + s_dbias[u];
            float gf = s_g[128 + u][r] + s_dbias[128 + u];
            float gg = s_g[256 + u][r] + s_dbias[256 + u];
            float go = s_g[384 + u][r] + s_dbias[384 + u];
            float c = sigf(gf) * s_c[r][u] + sigf(gi) * tanhff(gg);
            float h = sigf(go) * tanhff(c);
            s_c[r][u] = c;
            u16 hi = f2b(h);
            s_Adec[r][256 + u] = hi;
            s_Adec[r][384 + u] = f2b(h - b2f(hi));
        }
        __syncthreads();

        // D7: head y1 = tanh(h(hi/lo) @ fc_w + fc_b) (4 waves)
        if (wv < 4) {
            const int n = wv * 16 + l16;
            f32x4 acc = {0.f,0.f,0.f,0.f};
            const u16* bp = g_fcwT + s * 8192 + n * 128 + quad * 8;
#pragma unroll
            for (int c = 0; c < 8; ++c) {
                short8 av = *(const short8*)&s_Adec[l16][256 + c*32 + quad*8];
                acc = MFMA16(av, *(const short8*)(bp + (c&3)*32), acc);
            }
            float fb = fcb[s * 64 + n];
            if (quad < 2) {
#pragma unroll
                for (int rg = 0; rg < 4; ++rg) s_y1[quad*4 + rg][n] = tanhff(acc[rg] + fb);
            }
        }
        __syncthreads();

        // D8: out = sigmoid(y1 @ out_w + out_b)
        if (tid < 512) {
            const int r = tid >> 6;
            float v = s_y1[r][lane] * ow[s * 64 + lane];
#pragma unroll
            for (int m = 1; m < 64; m <<= 1) v += __shfl_xor(v, m, 64);
            if (lane == 0) out[(b0 + r) * NOUT + s] = sigf(v + ob[s]);
        }
        __syncthreads();
    }
}

extern "C" void kernel_launch(void* const* d_in, const int* in_sizes, int n_in,
                              void* d_out, int out_size, void* d_ws, size_t ws_size,
                              hipStream_t stream) {
    const float* x    = (const float*)d_in[0];
    const float* eWih = (const float*)d_in[1];
    const float* eWhh = (const float*)d_in[2];
    const float* ebih = (const float*)d_in[3];
    const float* ebhh = (const float*)d_in[4];
    const float* aw   = (const float*)d_in[5];
    const float* ab   = (const float*)d_in[6];
    const float* dWih = (const float*)d_in[7];
    const float* dWhh = (const float*)d_in[8];
    const float* dbih = (const float*)d_in[9];
    const float* dbhh = (const float*)d_in[10];
    const float* ddw  = (const float*)d_in[11];
    const float* ddb  = (const float*)d_in[12];
    const float* dlw  = (const float*)d_in[13];
    const float* dlb  = (const float*)d_in[14];
    const float* fcw  = (const float*)d_in[15];
    const float* fcb  = (const float*)d_in[16];
    const float* ow   = (const float*)d_in[17];
    const float* ob   = (const float*)d_in[18];
    float* out = (float*)d_out;

    convert_kernel<<<1024, 256, 0, stream>>>(x, eWih, eWhh, dWih, dWhh, ddw, fcw);
    conv_awT<<<LK, 256, 0, stream>>>(aw);
    darnn_kernel<<<NWG, NTHR, 0, stream>>>(ab, ebih, ebhh, dbih, dbhh, ddb,
                                           dlw, dlb, fcb, ow, ob, out);
}

// Round 10
// 413.667 us; speedup vs baseline: 1.8183x; 1.0431x over previous
//
#include <hip/hip_runtime.h>

#define LK   50      // look_back
#define NOUT 3
#define FF   64      // feature_num
#define BB   2048    // batch
#define BT   8       // batch rows per workgroup
#define NWG  (BB/BT) // 256 workgroups
#define NTHR 1024    // 16 waves

typedef unsigned short u16;
typedef unsigned int   u32;
typedef __attribute__((ext_vector_type(8))) short short8;
typedef __attribute__((ext_vector_type(4))) float f32x4;

#define MFMA16(a,b,c) __builtin_amdgcn_mfma_f32_16x16x32_bf16(a,b,c,0,0,0)

// pre-converted bf16 weight buffers (device globals; rewritten every launch)
__device__ u16 g_awT [(size_t)LK*64*192];  // attn_w^T, [t][c][k]  k:[xt(64)|h(128)]
__device__ u16 g_eW  [512*192];            // enc LSTM, [gate][k]  k:[xin(64)|h(128)]
__device__ u16 g_dW  [512*384];            // dec LSTM, [gate][k]  k:[ctx(128)|h(128)|h(128)]
__device__ u16 g_ddwT[NOUT*128*256];       // dd_w^T,   [s][n][k]  k:[enc(128)|h(128)]
__device__ u16 g_fcwT[NOUT*64*128];        // fc_w^T,   [s][n][k]
__device__ u16 g_encbf[(size_t)BB*LK*256]; // encoder outputs hi/lo: [b][t][hi(128)|lo(128)]

__device__ __forceinline__ float sigf(float x) { return 1.0f / (1.0f + __expf(-x)); }
__device__ __forceinline__ float tanhff(float x) { return 1.0f - 2.0f / (__expf(2.0f * x) + 1.0f); }
__device__ __forceinline__ u16 f2b(float f) {
    union { float f; u32 u; } v; v.f = f;
    u32 r = v.u + 0x7fffu + ((v.u >> 16) & 1u);
    return (u16)(r >> 16);
}
__device__ __forceinline__ float b2f(u16 h) {
    union { u32 u; float f; } v; v.u = ((u32)h) << 16; return v.f;
}

// weights-only convert (x handled inline by darnn; awT by conv_awT)
__global__ __launch_bounds__(256)
void convert_kernel(const float* __restrict__ eWih, const float* __restrict__ eWhh,
                    const float* __restrict__ dWih, const float* __restrict__ dWhh,
                    const float* __restrict__ ddw,  const float* __restrict__ fcw)
{
    const int gid = blockIdx.x * blockDim.x + threadIdx.x;
    const int stride = gridDim.x * blockDim.x;
    for (int i = gid; i < 512*192; i += stride) {
        int j = i / 192, k = i % 192;
        g_eW[i] = f2b(k < 64 ? eWih[j*64 + k] : eWhh[j*128 + (k-64)]);
    }
    for (int i = gid; i < 512*384; i += stride) {
        int j = i / 384, k = i % 384;
        g_dW[i] = f2b(k < 256 ? dWih[j*256 + k] : dWhh[j*128 + (k-256)]);
    }
    for (int i = gid; i < NOUT*256*128; i += stride) {
        int s = i / 32768, rm = i % 32768, k = rm / 128, n = rm % 128;
        g_ddwT[(size_t)s*32768 + n*256 + k] = f2b(ddw[i]);
    }
    for (int i = gid; i < NOUT*128*64; i += stride) {
        int s = i / 8192, rm = i % 8192, k = rm / 64, n = rm % 64;
        g_fcwT[(size_t)s*8192 + n*128 + k] = f2b(fcw[i]);
    }
}

// LDS-tiled awT transpose: one block per t; coalesced read AND write
__global__ __launch_bounds__(256)
void conv_awT(const float* __restrict__ aw)
{
    __shared__ u16 tile[192*66];
    const int t = blockIdx.x, tid = threadIdx.x;
    for (int i = tid; i < 192*64; i += 256) {
        int k = i >> 6, c = i & 63;
        tile[k*66 + c] = f2b(aw[(size_t)t*12288 + i]);
    }
    __syncthreads();
    u32* dst = (u32*)g_awT + (size_t)t * 6144;
    for (int j = tid; j < 6144; j += 256) {
        int c = j / 96, w = j % 96;
        dst[j] = (u32)tile[(2*w)*66 + c] | ((u32)tile[(2*w+1)*66 + c] << 16);
    }
}

__global__ __launch_bounds__(NTHR, 4)
void darnn_kernel(const float* __restrict__ x,
                  const float* __restrict__ ab,
                  const float* __restrict__ ebih, const float* __restrict__ ebhh,
                  const float* __restrict__ dbih, const float* __restrict__ dbhh,
                  const float* __restrict__ ddb,
                  const float* __restrict__ dlw,  const float* __restrict__ dlb,
                  const float* __restrict__ fcb,
                  const float* __restrict__ ow,   const float* __restrict__ ob,
                  float* __restrict__ out)
{
    // hi/lo FOLDED into M: rows 0-7 = hi, rows 8-15 = lo (same K, same B)
    __shared__ u16  s_x[2][16][80];     // x(t) ping-pong; rows 8-15 zero
    __shared__ u16  s_xin[16][80];      // xin; rows 8-15 zero
    __shared__ u16  s_h[16][144];       // enc h: row r<8 = hi[r], row r>=8 = lo[r-8]
    __shared__ u16  s_Adec[16][272];    // dec A: [ctx(0:128)|h(128:256)], hi rows 0-7 / lo rows 8-15
    __shared__ float s_e[8][64];        // attn pre-tanh scores
    __shared__ float s_c[8][128];       // cell state fp32
    __shared__ float s_g[512][9];       // gate partials
    __shared__ float s_hp[8][128];      // decoder hpart
    __shared__ float s_spart[4][400];   // score partials
    __shared__ float s_alpha[8][64];    // temporal attn weights
    __shared__ float s_y1[8][64];       // head intermediate
    __shared__ float s_ebias[512];
    __shared__ float s_dbias[512];

    const int tid  = threadIdx.x;
    const int b0   = blockIdx.x * BT;
    const int wv   = tid >> 6;
    const int lane = tid & 63;
    const int quad = lane >> 4;
    const int l16  = lane & 15;
    const int n0   = wv * 32;           // this wave's 2 gate n-tiles

    // ---- preamble ----
    for (int i = tid; i < 2*16*80; i += NTHR) (&s_x[0][0][0])[i] = 0;
    for (int i = tid; i < 16*80;   i += NTHR) (&s_xin[0][0])[i] = 0;
    for (int i = tid; i < 16*144;  i += NTHR) (&s_h[0][0])[i] = 0;
    for (int i = tid; i < 16*272;  i += NTHR) (&s_Adec[0][0])[i] = 0;
    (&s_c[0][0])[tid] = 0.0f;
    if (tid < 512) { s_ebias[tid] = ebih[tid] + ebhh[tid]; s_dbias[tid] = dbih[tid] + dbhh[tid]; }
    if (tid < 512) {
        int r = tid >> 6, f = tid & 63;
        s_x[0][r][f] = f2b(x[((size_t)(b0 + r) * LK + 0) * FF + f]);
    }
    // pin full eW B-set: 2 tiles x 6 K-chunks = 12 short8 = 48 VGPRs, whole t-loop
    short8 wf[12];
#pragma unroll
    for (int nn = 0; nn < 2; ++nn)
#pragma unroll
        for (int uc = 0; uc < 6; ++uc)
            wf[nn*6+uc] = *(const short8*)(g_eW + (size_t)(n0 + nn*16 + l16) * 192 + uc*32 + quad*8);
    __syncthreads();

    // ================= ENCODER: 50 steps, 4 barriers each =================
#pragma unroll 1
    for (int t = 0; t < LK; ++t) {
        const int pb = t & 1;

        // --- P1: attention e (waves 0-3), K=192, lo folded into rows 8-15 ---
        if (wv < 4) {
            const int f0 = wv * 16 + l16;
            const u16* bp = g_awT + (size_t)t * 12288 + f0 * 192 + quad * 8;
            short8 bfr[6];
#pragma unroll
            for (int uc = 0; uc < 6; ++uc) bfr[uc] = *(const short8*)(bp + uc*32);
            f32x4 acc = {0.f,0.f,0.f,0.f};
#pragma unroll
            for (int c = 0; c < 6; ++c) {
                const u16* ap = (c < 2) ? &s_x[pb][l16][c*32 + quad*8]
                                        : &s_h[l16][(c-2)*32 + quad*8];
                acc = MFMA16(*(const short8*)ap, bfr[c], acc);
            }
            float ev[4];
#pragma unroll
            for (int rg = 0; rg < 4; ++rg) ev[rg] = acc[rg] + __shfl_xor(acc[rg], 32, 64);
            const float abv = ab[t * FF + f0];
            if (quad < 2) {
#pragma unroll
                for (int rg = 0; rg < 4; ++rg) s_e[quad*4 + rg][f0] = ev[rg] + abv;
            }
        }
        __syncthreads();

        // --- P2: softmax (waves 0-7) || x(t+1) fp32->bf16 prefetch (waves 8-11) ---
        if (tid < 512) {
            const int r = tid >> 6;
            float e = tanhff(s_e[r][lane]);
            float mx = e;
#pragma unroll
            for (int m = 1; m < 64; m <<= 1) mx = fmaxf(mx, __shfl_xor(mx, m, 64));
            float ex = __expf(e - mx);
            float sm = ex;
#pragma unroll
            for (int m = 1; m < 64; m <<= 1) sm += __shfl_xor(sm, m, 64);
            s_xin[r][lane] = f2b(ex / sm * b2f(s_x[pb][r][lane]));
        } else if (tid < 768) {
            if (t + 1 < LK) {
                const int ii = tid - 512;            // 0..255
                const int r = ii >> 5, p = ii & 31;  // 2 floats per thread
                const float2 xv = *(const float2*)(x + ((size_t)(b0 + r) * LK + (t + 1)) * FF + 2*p);
                *((u32*)&s_x[pb^1][r][0] + p) = (u32)f2b(xv.x) | ((u32)f2b(xv.y) << 16);
            }
        }
        __syncthreads();

        // --- P3: gate GEMM, 16 waves, zero loads, K=192 (lo folded) ---
        {
            f32x4 a0 = {0.f,0.f,0.f,0.f}, a1 = {0.f,0.f,0.f,0.f};
#pragma unroll
            for (int c = 0; c < 6; ++c) {
                const u16* ap = (c < 2) ? &s_xin[l16][c*32 + quad*8]
                                        : &s_h[l16][(c-2)*32 + quad*8];
                short8 av = *(const short8*)ap;
                a0 = MFMA16(av, wf[c],   a0);
                a1 = MFMA16(av, wf[6+c], a1);
            }
            float v0[4], v1[4];
#pragma unroll
            for (int rg = 0; rg < 4; ++rg) {
                v0[rg] = a0[rg] + __shfl_xor(a0[rg], 32, 64);
                v1[rg] = a1[rg] + __shfl_xor(a1[rg], 32, 64);
            }
            if (quad < 2) {
#pragma unroll
                for (int rg = 0; rg < 4; ++rg) {
                    int r = quad*4 + rg;
                    s_g[n0 + l16][r]      = v0[rg];
                    s_g[n0 + 16 + l16][r] = v1[rg];
                }
            }
        }
        __syncthreads();

        // --- P4: gate combine + state update (hi/lo rows) + enc store ---
        {
            const int u = tid & 127, r = tid >> 7;
            float gi = s_g[u][r]       + s_ebias[u];
            float gf = s_g[128 + u][r] + s_ebias[128 + u];
            float gg = s_g[256 + u][r] + s_ebias[256 + u];
            float go = s_g[384 + u][r] + s_ebias[384 + u];
            float c = sigf(gf) * s_c[r][u] + sigf(gi) * tanhff(gg);
            float h = sigf(go) * tanhff(c);
            s_c[r][u] = c;
            u16 hi = f2b(h);
            u16 lo = f2b(h - b2f(hi));
            s_h[r][u]     = hi;
            s_h[r + 8][u] = lo;
            size_t eb = ((size_t)(b0 + r) * LK + t) * 256;
            g_encbf[eb + u]       = hi;
            g_encbf[eb + 128 + u] = lo;
        }
        __syncthreads();
    }

    // ================= DECODER: 3 steps =================
    (&s_c[0][0])[tid] = 0.0f;   // s_Adec still zero from init
    __syncthreads();

#pragma unroll 1
    for (int s = 0; s < NOUT; ++s) {
        // D1: hpart = h_de @ ddw[128:,:] + ddb  (8 waves, K=128, lo folded)
        if (wv < 8) {
            const int n = wv * 16 + l16;
            f32x4 acc = {0.f,0.f,0.f,0.f};
            const u16* bp = g_ddwT + s * 32768 + n * 256 + 128 + quad * 8;
#pragma unroll
            for (int c = 0; c < 4; ++c) {
                short8 av = *(const short8*)&s_Adec[l16][128 + c*32 + quad*8];
                acc = MFMA16(av, *(const short8*)(bp + c*32), acc);
            }
            float vv[4];
#pragma unroll
            for (int rg = 0; rg < 4; ++rg) vv[rg] = acc[rg] + __shfl_xor(acc[rg], 32, 64);
            const float db = ddb[s * 128 + n];
            if (quad < 2) {
#pragma unroll
                for (int rg = 0; rg < 4; ++rg) s_hp[quad*4 + rg][n] = vv[rg] + db;
            }
        }
        __syncthreads();

        // D2: score GEMM [400, 256-A(hi/lo as K)] x [128-B, 128] — rows full, unchanged
        {
            const int np = wv & 3, mq = wv >> 2, nb0 = np * 32;
            short8 bfr[8];
            const u16* bp = g_ddwT + s * 32768 + (nb0 + l16) * 256 + quad * 8;
#pragma unroll
            for (int nn = 0; nn < 2; ++nn)
#pragma unroll
                for (int ks = 0; ks < 4; ++ks)
                    bfr[nn*4+ks] = *(const short8*)(bp + nn*4096 + ks*32);
            const float dl0 = dlw[s*128 + nb0 + l16];
            const float dl1 = dlw[s*128 + nb0 + 16 + l16];
#pragma unroll 1
            for (int mt = mq; mt < 25; mt += 4) {
                const u16* ap = g_encbf + ((size_t)b0 * LK + mt*16 + l16) * 256 + quad * 8;
                f32x4 a0 = {0.f,0.f,0.f,0.f}, a1 = {0.f,0.f,0.f,0.f};
#pragma unroll
                for (int c = 0; c < 8; ++c) {
                    short8 av = *(const short8*)(ap + c*32);
                    a0 = MFMA16(av, bfr[c&3],     a0);
                    a1 = MFMA16(av, bfr[4+(c&3)], a1);
                }
#pragma unroll
                for (int rg = 0; rg < 4; ++rg) {
                    int rt = mt*16 + quad*4 + rg;
                    int r  = rt / LK;
                    float v = tanhff(a0[rg] + s_hp[r][nb0 + l16]) * dl0
                            + tanhff(a1[rg] + s_hp[r][nb0 + 16 + l16]) * dl1;
                    v += __shfl_xor(v, 1, 64); v += __shfl_xor(v, 2, 64);
                    v += __shfl_xor(v, 4, 64); v += __shfl_xor(v, 8, 64);
                    if (l16 == 0) s_spart[np][rt] = v;
                }
            }
        }
        __syncthreads();

        // D3: softmax over t (wave per row)
        if (tid < 512) {
            const int r = tid >> 6;
            float sv = (lane < LK)
                ? (s_spart[0][r*LK + lane] + s_spart[1][r*LK + lane] +
                   s_spart[2][r*LK + lane] + s_spart[3][r*LK + lane] + dlb[s])
                : -1e30f;
            float mx = sv;
#pragma unroll
            for (int m = 1; m < 64; m <<= 1) mx = fmaxf(mx, __shfl_xor(mx, m, 64));
            float ex = (lane < LK) ? __expf(sv - mx) : 0.0f;
            float sm = ex;
#pragma unroll
            for (int m = 1; m < 64; m <<= 1) sm += __shfl_xor(sm, m, 64);
            if (lane < LK) s_alpha[r][lane] = ex / sm;
        }
        __syncthreads();

        // D4: ctx = sum_t alpha * (enc_hi + enc_lo) in fp32; store hi/lo rows
        {
            const int jd = tid & 127, r = tid >> 7;
            const u16* ep = g_encbf + (size_t)(b0 + r) * LK * 256 + jd;
            float a = 0.0f;
#pragma unroll 10
            for (int tt = 0; tt < LK; ++tt)
                a += s_alpha[r][tt] * (b2f(ep[tt*256]) + b2f(ep[tt*256 + 128]));
            u16 hi = f2b(a);
            s_Adec[r][jd]     = hi;
            s_Adec[r + 8][jd] = f2b(a - b2f(hi));
        }
        __syncthreads();

        // D5: decoder LSTM gates, K=384 (lo folded into rows) — 12 chunks/wave
        {
            const int nd0 = wv * 32;
            f32x4 a0 = {0.f,0.f,0.f,0.f}, a1 = {0.f,0.f,0.f,0.f};
            const u16* bp0 = g_dW + (nd0 + l16) * 384 + quad * 8;
            const u16* bp1 = bp0 + 16 * 384;
#pragma unroll
            for (int c = 0; c < 12; ++c) {
                const int g = c >> 2, o = (c & 3) * 32;
                const int aoff = (g == 0 ? 0 : 128) + o;   // ctx | h | h(same)
                const int boff = g * 128 + o;
                short8 av = *(const short8*)&s_Adec[l16][aoff + quad*8];
                a0 = MFMA16(av, *(const short8*)(bp0 + boff), a0);
                a1 = MFMA16(av, *(const short8*)(bp1 + boff), a1);
            }
            float v0[4], v1[4];
#pragma unroll
            for (int rg = 0; rg < 4; ++rg) {
                v0[rg] = a0[rg] + __shfl_xor(a0[rg], 32, 64);
                v1[rg] = a1[rg] + __shfl_xor(a1[rg], 32, 64);
            }
            if (quad < 2) {
#pragma unroll
                for (int rg = 0; rg < 4; ++rg) {
                    int r = quad*4 + rg;
                    s_g[nd0 + l16][r]      = v0[rg];
                    s_g[nd0 + 16 + l16][r] = v1[rg];
                }
            }
        }
        __syncthreads();

        // D6: gate combine + state update (hi/lo rows)
        {
            const int u = tid & 127, r = tid >> 7;
            float gi = s_g[u][r]       + s_dbias[u];
            float gf = s_g[128 + u][r] + s_dbias[128 + u];
            float gg = s_g[256 + u][r] + s_dbias[256 + u];
            float go = s_g[384 + u][r] + s_dbias[384 + u];
            float c = sigf(gf) * s_c[r][u] + sigf(gi) * tanhff(gg);
            float h = sigf(go) * tanhff(c);
            s_c[r][u] = c;
            u16 hi = f2b(h);
            s_Adec[r][128 + u]     = hi;
            s_Adec[r + 8][128 + u] = f2b(h - b2f(hi));
        }
        __syncthreads();

        // D7: head y1 = tanh(h @ fc_w + fc_b) (4 waves, K=128, lo folded)
        if (wv < 4) {
            const int n = wv * 16 + l16;
            f32x4 acc = {0.f,0.f,0.f,0.f};
            const u16* bp = g_fcwT + s * 8192 + n * 128 + quad * 8;
#pragma unroll
            for (int c = 0; c < 4; ++c) {
                short8 av = *(const short8*)&s_Adec[l16][128 + c*32 + quad*8];
                acc = MFMA16(av, *(const short8*)(bp + c*32), acc);
            }
            float vv[4];
#pragma unroll
            for (int rg = 0; rg < 4; ++rg) vv[rg] = acc[rg] + __shfl_xor(acc[rg], 32, 64);
            const float fb = fcb[s * 64 + n];
            if (quad < 2) {
#pragma unroll
                for (int rg = 0; rg < 4; ++rg) s_y1[quad*4 + rg][n] = tanhff(vv[rg] + fb);
            }
        }
        __syncthreads();

        // D8: out = sigmoid(y1 @ out_w + out_b)
        if (tid < 512) {
            const int r = tid >> 6;
            float v = s_y1[r][lane] * ow[s * 64 + lane];
#pragma unroll
            for (int m = 1; m < 64; m <<= 1) v += __shfl_xor(v, m, 64);
            if (lane == 0) out[(b0 + r) * NOUT + s] = sigf(v + ob[s]);
        }
        __syncthreads();
    }
}

extern "C" void kernel_launch(void* const* d_in, const int* in_sizes, int n_in,
                              void* d_out, int out_size, void* d_ws, size_t ws_size,
                              hipStream_t stream) {
    const float* x    = (const float*)d_in[0];
    const float* eWih = (const float*)d_in[1];
    const float* eWhh = (const float*)d_in[2];
    const float* ebih = (const float*)d_in[3];
    const float* ebhh = (const float*)d_in[4];
    const float* aw   = (const float*)d_in[5];
    const float* ab   = (const float*)d_in[6];
    const float* dWih = (const float*)d_in[7];
    const float* dWhh = (const float*)d_in[8];
    const float* dbih = (const float*)d_in[9];
    const float* dbhh = (const float*)d_in[10];
    const float* ddw  = (const float*)d_in[11];
    const float* ddb  = (const float*)d_in[12];
    const float* dlw  = (const float*)d_in[13];
    const float* dlb  = (const float*)d_in[14];
    const float* fcw  = (const float*)d_in[15];
    const float* fcb  = (const float*)d_in[16];
    const float* ow   = (const float*)d_in[17];
    const float* ob   = (const float*)d_in[18];
    float* out = (float*)d_out;

    convert_kernel<<<512, 256, 0, stream>>>(eWih, eWhh, dWih, dWhh, ddw, fcw);
    conv_awT<<<LK, 256, 0, stream>>>(aw);
    darnn_kernel<<<NWG, NTHR, 0, stream>>>(x, ab, ebih, ebhh, dbih, dbhh, ddb,
                                           dlw, dlb, fcb, ow, ob, out);
}